// Round 1
// baseline (230.288 us; speedup 1.0000x reference)
//
#include <hip/hip_runtime.h>
#include <cstdint>

#define TB 16
#define TS 512
#define TD 512
#define TH 8
#define TDH 64
#define TSD (TS*TD)   // 262144

typedef __attribute__((ext_vector_type(8))) short s16x8;
typedef __attribute__((ext_vector_type(4))) float f32x4;
typedef unsigned short bfu;

__device__ __forceinline__ unsigned short f2b(float f) {
  unsigned int u = __float_as_uint(f);
  u += 0x7FFFu + ((u >> 16) & 1u);          // RNE to bf16
  return (unsigned short)(u >> 16);
}

__device__ __forceinline__ void gll16(const void* g, void* l) {
  __builtin_amdgcn_global_load_lds((const __attribute__((address_space(1))) void*)g,
                                   (__attribute__((address_space(3))) void*)l, 16, 0, 0);
}

__device__ __forceinline__ f32x4 MFMA16(s16x8 a, s16x8 b, f32x4 c) {
  return __builtin_amdgcn_mfma_f32_16x16x32_bf16(a, b, c, 0, 0, 0);
}

// ---------------- K0a: cast x (fp32 -> bf16) ----------------
__global__ __launch_bounds__(256) void k_cast_x(const float4* __restrict__ x, ushort4* __restrict__ xb) {
  int i = blockIdx.x * 256 + threadIdx.x;
  float4 v = x[i];
  ushort4 o; o.x = f2b(v.x); o.y = f2b(v.y); o.z = f2b(v.z); o.w = f2b(v.w);
  xb[i] = o;
}

// ---------------- K0b: build W^T bf16 [1536][512] (rows: 0-511 Q, 512-1023 K, 1024-1535 V) ----------------
__global__ __launch_bounds__(256) void k_prep_w(const float* __restrict__ WQ, const float* __restrict__ WK,
                                                const float* __restrict__ WV, bfu* __restrict__ wt) {
  __shared__ float tile[64][65];
  int bk = blockIdx.x & 7;           // k-tile (512/64)
  int bn = blockIdx.x >> 3;          // 0..23 n-tile
  const float* W = bn < 8 ? WQ : (bn < 16 ? WK : WV);
  int ncol0 = (bn & 7) * 64;
  int t = threadIdx.x, tx = t & 63, ty = t >> 6;
  #pragma unroll
  for (int i = 0; i < 16; ++i) {
    int kl = i * 4 + ty;
    tile[kl][tx] = W[(size_t)(bk * 64 + kl) * 512 + ncol0 + tx];
  }
  __syncthreads();
  #pragma unroll
  for (int i = 0; i < 16; ++i) {
    int nl = i * 4 + ty;
    wt[(size_t)(bn * 64 + nl) * 512 + bk * 64 + tx] = f2b(tile[tx][nl]);
  }
}

// ---------------- K1: QKV GEMM, 128x128 tile, BK=32, global_load_lds (m97 structure) ----------------
// C[m][n] = sum_k xb[m][k] * wt[n][k].  Q,K -> row-major [8192][512]; V -> transposed vtb[b][h][dh][S].
__global__ __launch_bounds__(256) void k_qkv(const bfu* __restrict__ xb, const bfu* __restrict__ wt,
                                             bfu* __restrict__ qb, bfu* __restrict__ kb, bfu* __restrict__ vtb) {
  __shared__ __align__(16) bfu At[128 * 32];
  __shared__ __align__(16) bfu Bt[128 * 32];
  int t = threadIdx.x, lane = t & 63, w = t >> 6;
  int wr = w >> 1, wc = w & 1;
  int m0 = blockIdx.x * 128, n0 = blockIdx.y * 128;
  int fr = lane & 15, hi = lane >> 4;
  f32x4 acc[4][4] = {};
  for (int k0 = 0; k0 < TD; k0 += 32) {
    #pragma unroll
    for (int i = 0; i < 2; ++i) {
      int base = (i * 4 + w) * 1024;           // bytes, wave-uniform
      int seg  = (i * 4 + w) * 64 + lane;      // 0..511
      int row = seg >> 2, cs = seg & 3;        // 4 x 16B segs per 32-elem row
      gll16(xb + (size_t)(m0 + row) * TD + k0 + cs * 8, (char*)At + base);
      gll16(wt + (size_t)(n0 + row) * TD + k0 + cs * 8, (char*)Bt + base);
    }
    __syncthreads();
    s16x8 a[4], bb[4];
    #pragma unroll
    for (int m = 0; m < 4; ++m) a[m]  = *(const s16x8*)&At[(wr * 64 + m * 16 + fr) * 32 + hi * 8];
    #pragma unroll
    for (int n = 0; n < 4; ++n) bb[n] = *(const s16x8*)&Bt[(wc * 64 + n * 16 + fr) * 32 + hi * 8];
    #pragma unroll
    for (int m = 0; m < 4; ++m)
      #pragma unroll
      for (int n = 0; n < 4; ++n)
        acc[m][n] = MFMA16(a[m], bb[n], acc[m][n]);
    __syncthreads();
  }
  #pragma unroll
  for (int m = 0; m < 4; ++m) {
    int grow = m0 + wr * 64 + m * 16 + hi * 4;
    #pragma unroll
    for (int n = 0; n < 4; ++n) {
      int gcol = n0 + wc * 64 + n * 16 + fr;
      if (gcol < 512) {
        #pragma unroll
        for (int r = 0; r < 4; ++r) qb[(size_t)(grow + r) * TD + gcol] = f2b(acc[m][n][r]);
      } else if (gcol < 1024) {
        int c = gcol - 512;
        #pragma unroll
        for (int r = 0; r < 4; ++r) kb[(size_t)(grow + r) * TD + c] = f2b(acc[m][n][r]);
      } else {
        int c = gcol - 1024;
        int hh = c >> 6, dc = c & 63;
        int b_ = grow >> 9, s = grow & 511;
        ushort4 pk;
        pk.x = f2b(acc[m][n][0]); pk.y = f2b(acc[m][n][1]);
        pk.z = f2b(acc[m][n][2]); pk.w = f2b(acc[m][n][3]);
        *(ushort4*)&vtb[((size_t)((b_ * TH + hh) * TDH + dc) << 9) + s] = pk;
      }
    }
  }
}

// ---------------- K2: attention per (qtile=64, h, b): S=QK^T/8, swish, P@V, +x residual ----------------
__global__ __launch_bounds__(256) void k_attn(const bfu* __restrict__ qb, const bfu* __restrict__ kb,
                                              const bfu* __restrict__ vtb, const float* __restrict__ x,
                                              float* __restrict__ ao) {
  __shared__ __align__(16) bfu Qs[64 * 72];    // padded: 2-way-free frag reads
  __shared__ __align__(16) bfu Ks[128 * 72];
  __shared__ __align__(16) bfu Vs[64 * 136];   // [dh][keys] (pre-transposed V)
  __shared__ __align__(16) bfu Ps[64 * 136];   // [q][keys] swished scores, bf16
  int t = threadIdx.x, lane = t & 63, w = t >> 6;
  int qt = blockIdx.x, h = blockIdx.y, b = blockIdx.z;
  size_t qrow0 = (size_t)b * TS + qt * 64;
  int fr = lane & 15, hi = lane >> 4;
  #pragma unroll
  for (int i = 0; i < 2; ++i) {    // stage Q once: 64x64
    int seg = i * 256 + t, row = seg >> 3, cs = seg & 7;
    s16x8 v = *(const s16x8*)(qb + (qrow0 + row) * TD + h * TDH + cs * 8);
    *(s16x8*)&Qs[row * 72 + cs * 8] = v;
  }
  f32x4 acc_o[4] = {};
  for (int kt = 0; kt < 4; ++kt) {
    #pragma unroll
    for (int i = 0; i < 4; ++i) {  // stage K tile 128x64
      int seg = i * 256 + t, row = seg >> 3, cs = seg & 7;
      s16x8 v = *(const s16x8*)(kb + ((size_t)b * TS + kt * 128 + row) * TD + h * TDH + cs * 8);
      *(s16x8*)&Ks[row * 72 + cs * 8] = v;
    }
    #pragma unroll
    for (int i = 0; i < 4; ++i) {  // stage V^T tile 64x128
      int seg = i * 256 + t, row = seg >> 4, cs = seg & 15;
      s16x8 v = *(const s16x8*)(vtb + ((size_t)(b * TH + h) * TDH + row) * TS + kt * 128 + cs * 8);
      *(s16x8*)&Vs[row * 136 + cs * 8] = v;
    }
    __syncthreads();
    // S = Q K^T : wave's 16 q-rows x 128 keys
    s16x8 aq0 = *(const s16x8*)&Qs[(w * 16 + fr) * 72 + hi * 8];
    s16x8 aq1 = *(const s16x8*)&Qs[(w * 16 + fr) * 72 + 32 + hi * 8];
    f32x4 sc[8];
    #pragma unroll
    for (int kj = 0; kj < 8; ++kj) {
      s16x8 b0 = *(const s16x8*)&Ks[(kj * 16 + fr) * 72 + hi * 8];
      s16x8 b1 = *(const s16x8*)&Ks[(kj * 16 + fr) * 72 + 32 + hi * 8];
      f32x4 c = {};
      c = MFMA16(aq0, b0, c);
      c = MFMA16(aq1, b1, c);
      sc[kj] = c;
    }
    // swish(S/8) -> bf16 P
    #pragma unroll
    for (int kj = 0; kj < 8; ++kj) {
      #pragma unroll
      for (int r = 0; r < 4; ++r) {
        float v = sc[kj][r] * 0.125f;
        float p = v / (1.f + __expf(-v));
        Ps[(w * 16 + hi * 4 + r) * 136 + kj * 16 + fr] = f2b(p);
      }
    }
    __syncthreads();   // P visible (cheap insurance, also covers lane-crossing within wave)
    // O += P @ V
    #pragma unroll
    for (int ks = 0; ks < 4; ++ks) {
      s16x8 pa = *(const s16x8*)&Ps[(w * 16 + fr) * 136 + ks * 32 + hi * 8];
      #pragma unroll
      for (int dn = 0; dn < 4; ++dn) {
        s16x8 vb = *(const s16x8*)&Vs[(dn * 16 + fr) * 136 + ks * 32 + hi * 8];
        acc_o[dn] = MFMA16(pa, vb, acc_o[dn]);
      }
    }
    __syncthreads();
  }
  #pragma unroll
  for (int dn = 0; dn < 4; ++dn) {
    int col = h * TDH + dn * 16 + fr;
    #pragma unroll
    for (int r = 0; r < 4; ++r) {
      size_t row = qrow0 + w * 16 + hi * 4 + r;
      ao[row * TD + col] = acc_o[dn][r] + x[row * TD + col];   // fused residual
    }
  }
}

// ---------------- K3: LayerNorm over D=512 (TF-style, eps=1e-12) ----------------
__global__ __launch_bounds__(256) void k_ln(const float* __restrict__ a, const float* __restrict__ w,
                                            const float* __restrict__ bias, float* __restrict__ o) {
  int row = blockIdx.x, t = threadIdx.x;
  float2 v = *(const float2*)(a + (size_t)row * TD + t * 2);
  float s = v.x + v.y;
  #pragma unroll
  for (int off = 32; off > 0; off >>= 1) s += __shfl_down(s, off);
  __shared__ float r1[4], r2[4];
  int lane = t & 63, wv = t >> 6;
  if (lane == 0) r1[wv] = s;
  __syncthreads();
  float mean = (r1[0] + r1[1] + r1[2] + r1[3]) * (1.f / TD);
  float dx = v.x - mean, dy = v.y - mean;
  float q = dx * dx + dy * dy;
  #pragma unroll
  for (int off = 32; off > 0; off >>= 1) q += __shfl_down(q, off);
  if (lane == 0) r2[wv] = q;
  __syncthreads();
  float var = (r2[0] + r2[1] + r2[2] + r2[3]) * (1.f / TD);
  float inv = rsqrtf(var + 1e-12f);
  float2 wv2 = *(const float2*)(w + t * 2);
  float2 bv2 = *(const float2*)(bias + t * 2);
  float2 ov; ov.x = wv2.x * dx * inv + bv2.x; ov.y = wv2.y * dy * inv + bv2.y;
  *(float2*)(o + (size_t)row * TD + t * 2) = ov;
}

// ---------------- K4: final linear partials: 512 K-chunks of 512, all 16 batch rows in regs ----------------
__global__ __launch_bounds__(256) void k_lin_part(const float* __restrict__ ln, const float* __restrict__ wl,
                                                  float* __restrict__ part) {
  __shared__ float al[512 * 20];   // [k][16 m-values + pad4], 40KB
  int t = threadIdx.x, blk = blockIdx.x;
  int k0 = blk * 512;
  #pragma unroll
  for (int m = 0; m < 16; ++m) {
    al[t * 20 + m]         = ln[(size_t)m * TSD + k0 + t];
    al[(256 + t) * 20 + m] = ln[(size_t)m * TSD + k0 + 256 + t];
  }
  __syncthreads();
  float acc0[16] = {}, acc1[16] = {};
  const float* wp = wl + (size_t)k0 * 512 + t * 2;
  #pragma unroll 4
  for (int k = 0; k < 512; ++k) {
    float2 wv = *(const float2*)(wp + (size_t)k * 512);
    const float* ar = &al[k * 20];
    float4 a0 = *(const float4*)(ar);
    float4 a1 = *(const float4*)(ar + 4);
    float4 a2 = *(const float4*)(ar + 8);
    float4 a3 = *(const float4*)(ar + 12);
    float av[16] = {a0.x, a0.y, a0.z, a0.w, a1.x, a1.y, a1.z, a1.w,
                    a2.x, a2.y, a2.z, a2.w, a3.x, a3.y, a3.z, a3.w};
    #pragma unroll
    for (int m = 0; m < 16; ++m) { acc0[m] += av[m] * wv.x; acc1[m] += av[m] * wv.y; }
  }
  #pragma unroll
  for (int m = 0; m < 16; ++m) {
    float2 pv; pv.x = acc0[m]; pv.y = acc1[m];
    *(float2*)&part[(size_t)blk * 8192 + m * 512 + t * 2] = pv;
  }
}

// ---------------- K5: reduce 512 partials + bias + swish ----------------
__global__ __launch_bounds__(256) void k_lin_red(const float* __restrict__ part, const float* __restrict__ blin,
                                                 float* __restrict__ out) {
  int o = blockIdx.x * 256 + threadIdx.x;   // 8192 outputs
  float s = 0.f;
  #pragma unroll 8
  for (int c = 0; c < 512; ++c) s += part[(size_t)c * 8192 + o];
  float v = s + blin[o & 511];
  out[o] = v / (1.f + __expf(-v));
}

extern "C" void kernel_launch(void* const* d_in, const int* in_sizes, int n_in,
                              void* d_out, int out_size, void* d_ws, size_t ws_size,
                              hipStream_t stream) {
  const float* x   = (const float*)d_in[0];
  const float* WQ  = (const float*)d_in[1];
  const float* WK  = (const float*)d_in[2];
  const float* WV  = (const float*)d_in[3];
  const float* Wl  = (const float*)d_in[4];
  const float* bl  = (const float*)d_in[5];
  const float* lnw = (const float*)d_in[6];
  const float* lnb = (const float*)d_in[7];
  float* out = (float*)d_out;
  char* ws = (char*)d_ws;
  // workspace layout (bf16 elems unless noted)
  bfu* xb  = (bfu*)ws;            // 4,194,304
  bfu* wt  = xb + 4194304;        //   786,432
  bfu* qb  = wt + 786432;         // 4,194,304
  bfu* kb  = qb + 4194304;        // 4,194,304
  bfu* vtb = kb + 4194304;        // 4,194,304
  float* attn = (float*)(vtb + 4194304);   // 4,194,304 f32
  float* lno  = attn + 4194304;            // 4,194,304 f32
  float* part = (float*)ws;       // reuse xb/wt/qb region (dead by then): 4,194,304 f32

  k_cast_x  <<<4096, 256, 0, stream>>>((const float4*)x, (ushort4*)xb);
  k_prep_w  <<<192, 256, 0, stream>>>(WQ, WK, WV, wt);
  k_qkv     <<<dim3(64, 12), 256, 0, stream>>>(xb, wt, qb, kb, vtb);
  k_attn    <<<dim3(8, 8, 16), 256, 0, stream>>>(qb, kb, vtb, x, attn);
  k_ln      <<<8192, 256, 0, stream>>>(attn, lnw, lnb, lno);
  k_lin_part<<<512, 256, 0, stream>>>(lno, Wl, part);
  k_lin_red <<<32, 256, 0, stream>>>(part, bl, out);
}

// Round 2
// 214.559 us; speedup vs baseline: 1.0733x; 1.0733x over previous
//
#include <hip/hip_runtime.h>
#include <cstdint>

#define TB 16
#define TS 512
#define TD 512
#define TH 8
#define TDH 64
#define TSD (TS*TD)   // 262144

typedef __attribute__((ext_vector_type(8))) short s16x8;
typedef __attribute__((ext_vector_type(4))) float f32x4;
typedef unsigned short bfu;

__device__ __forceinline__ unsigned short f2b(float f) {
  unsigned int u = __float_as_uint(f);
  u += 0x7FFFu + ((u >> 16) & 1u);          // RNE to bf16
  return (unsigned short)(u >> 16);
}
__device__ __forceinline__ float b2f(bfu h) {
  return __uint_as_float(((unsigned)h) << 16);
}

__device__ __forceinline__ void gll16(const void* g, void* l) {
  __builtin_amdgcn_global_load_lds((const __attribute__((address_space(1))) void*)g,
                                   (__attribute__((address_space(3))) void*)l, 16, 0, 0);
}

__device__ __forceinline__ f32x4 MFMA16(s16x8 a, s16x8 b, f32x4 c) {
  return __builtin_amdgcn_mfma_f32_16x16x32_bf16(a, b, c, 0, 0, 0);
}

// ---------------- K0a: cast x (fp32 -> bf16) ----------------
__global__ __launch_bounds__(256) void k_cast_x(const float4* __restrict__ x, ushort4* __restrict__ xb) {
  int i = blockIdx.x * 256 + threadIdx.x;
  float4 v = x[i];
  ushort4 o; o.x = f2b(v.x); o.y = f2b(v.y); o.z = f2b(v.z); o.w = f2b(v.w);
  xb[i] = o;
}

// ---------------- K0b: build W^T bf16 [1536][512] (rows: 0-511 Q, 512-1023 K, 1024-1535 V) ----------------
__global__ __launch_bounds__(256) void k_prep_w(const float* __restrict__ WQ, const float* __restrict__ WK,
                                                const float* __restrict__ WV, bfu* __restrict__ wt) {
  __shared__ float tile[64][65];
  int bk = blockIdx.x & 7;           // k-tile (512/64)
  int bn = blockIdx.x >> 3;          // 0..23 n-tile
  const float* W = bn < 8 ? WQ : (bn < 16 ? WK : WV);
  int ncol0 = (bn & 7) * 64;
  int t = threadIdx.x, tx = t & 63, ty = t >> 6;
  #pragma unroll
  for (int i = 0; i < 16; ++i) {
    int kl = i * 4 + ty;
    tile[kl][tx] = W[(size_t)(bk * 64 + kl) * 512 + ncol0 + tx];
  }
  __syncthreads();
  #pragma unroll
  for (int i = 0; i < 16; ++i) {
    int nl = i * 4 + ty;
    wt[(size_t)(bn * 64 + nl) * 512 + bk * 64 + tx] = f2b(tile[tx][nl]);
  }
}

// ---------------- K1: QKV GEMM, 128x128 tile, BK=32, global_load_lds (m97 structure) ----------------
__global__ __launch_bounds__(256) void k_qkv(const bfu* __restrict__ xb, const bfu* __restrict__ wt,
                                             bfu* __restrict__ qb, bfu* __restrict__ kb, bfu* __restrict__ vtb) {
  __shared__ __align__(16) bfu At[128 * 32];
  __shared__ __align__(16) bfu Bt[128 * 32];
  int t = threadIdx.x, lane = t & 63, w = t >> 6;
  int wr = w >> 1, wc = w & 1;
  int m0 = blockIdx.x * 128, n0 = blockIdx.y * 128;
  int fr = lane & 15, hi = lane >> 4;
  f32x4 acc[4][4] = {};
  for (int k0 = 0; k0 < TD; k0 += 32) {
    #pragma unroll
    for (int i = 0; i < 2; ++i) {
      int base = (i * 4 + w) * 1024;           // bytes, wave-uniform
      int seg  = (i * 4 + w) * 64 + lane;      // 0..511
      int row = seg >> 2, cs = seg & 3;        // 4 x 16B segs per 32-elem row
      gll16(xb + (size_t)(m0 + row) * TD + k0 + cs * 8, (char*)At + base);
      gll16(wt + (size_t)(n0 + row) * TD + k0 + cs * 8, (char*)Bt + base);
    }
    __syncthreads();
    s16x8 a[4], bb[4];
    #pragma unroll
    for (int m = 0; m < 4; ++m) a[m]  = *(const s16x8*)&At[(wr * 64 + m * 16 + fr) * 32 + hi * 8];
    #pragma unroll
    for (int n = 0; n < 4; ++n) bb[n] = *(const s16x8*)&Bt[(wc * 64 + n * 16 + fr) * 32 + hi * 8];
    #pragma unroll
    for (int m = 0; m < 4; ++m)
      #pragma unroll
      for (int n = 0; n < 4; ++n)
        acc[m][n] = MFMA16(a[m], bb[n], acc[m][n]);
    __syncthreads();
  }
  #pragma unroll
  for (int m = 0; m < 4; ++m) {
    int grow = m0 + wr * 64 + m * 16 + hi * 4;
    #pragma unroll
    for (int n = 0; n < 4; ++n) {
      int gcol = n0 + wc * 64 + n * 16 + fr;
      if (gcol < 512) {
        #pragma unroll
        for (int r = 0; r < 4; ++r) qb[(size_t)(grow + r) * TD + gcol] = f2b(acc[m][n][r]);
      } else if (gcol < 1024) {
        int c = gcol - 512;
        #pragma unroll
        for (int r = 0; r < 4; ++r) kb[(size_t)(grow + r) * TD + c] = f2b(acc[m][n][r]);
      } else {
        int c = gcol - 1024;
        int hh = c >> 6, dc = c & 63;
        int b_ = grow >> 9, s = grow & 511;
        ushort4 pk;
        pk.x = f2b(acc[m][n][0]); pk.y = f2b(acc[m][n][1]);
        pk.z = f2b(acc[m][n][2]); pk.w = f2b(acc[m][n][3]);
        *(ushort4*)&vtb[((size_t)((b_ * TH + hh) * TDH + dc) << 9) + s] = pk;
      }
    }
  }
}

// ---------------- K2: attention per (qtile=64, h, b): S=QK^T/8, swish, P@V, +xb residual ----------------
__global__ __launch_bounds__(256) void k_attn(const bfu* __restrict__ qb, const bfu* __restrict__ kb,
                                              const bfu* __restrict__ vtb, const bfu* __restrict__ xb,
                                              float* __restrict__ ao) {
  __shared__ __align__(16) bfu Qs[64 * 72];
  __shared__ __align__(16) bfu Ks[128 * 72];
  __shared__ __align__(16) bfu Vs[64 * 136];   // [dh][keys] (pre-transposed V)
  __shared__ __align__(16) bfu Ps[64 * 136];   // [q][keys] swished scores, bf16
  int t = threadIdx.x, lane = t & 63, w = t >> 6;
  int qt = blockIdx.x, h = blockIdx.y, b = blockIdx.z;
  size_t qrow0 = (size_t)b * TS + qt * 64;
  int fr = lane & 15, hi = lane >> 4;
  #pragma unroll
  for (int i = 0; i < 2; ++i) {    // stage Q once: 64x64
    int seg = i * 256 + t, row = seg >> 3, cs = seg & 7;
    s16x8 v = *(const s16x8*)(qb + (qrow0 + row) * TD + h * TDH + cs * 8);
    *(s16x8*)&Qs[row * 72 + cs * 8] = v;
  }
  f32x4 acc_o[4] = {};
  for (int kt = 0; kt < 4; ++kt) {
    #pragma unroll
    for (int i = 0; i < 4; ++i) {  // stage K tile 128x64
      int seg = i * 256 + t, row = seg >> 3, cs = seg & 7;
      s16x8 v = *(const s16x8*)(kb + ((size_t)b * TS + kt * 128 + row) * TD + h * TDH + cs * 8);
      *(s16x8*)&Ks[row * 72 + cs * 8] = v;
    }
    #pragma unroll
    for (int i = 0; i < 4; ++i) {  // stage V^T tile 64x128
      int seg = i * 256 + t, row = seg >> 4, cs = seg & 15;
      s16x8 v = *(const s16x8*)(vtb + ((size_t)(b * TH + h) * TDH + row) * TS + kt * 128 + cs * 8);
      *(s16x8*)&Vs[row * 136 + cs * 8] = v;
    }
    __syncthreads();
    s16x8 aq0 = *(const s16x8*)&Qs[(w * 16 + fr) * 72 + hi * 8];
    s16x8 aq1 = *(const s16x8*)&Qs[(w * 16 + fr) * 72 + 32 + hi * 8];
    f32x4 sc[8];
    #pragma unroll
    for (int kj = 0; kj < 8; ++kj) {
      s16x8 b0 = *(const s16x8*)&Ks[(kj * 16 + fr) * 72 + hi * 8];
      s16x8 b1 = *(const s16x8*)&Ks[(kj * 16 + fr) * 72 + 32 + hi * 8];
      f32x4 c = {};
      c = MFMA16(aq0, b0, c);
      c = MFMA16(aq1, b1, c);
      sc[kj] = c;
    }
    #pragma unroll
    for (int kj = 0; kj < 8; ++kj) {
      #pragma unroll
      for (int r = 0; r < 4; ++r) {
        float v = sc[kj][r] * 0.125f;
        float p = v / (1.f + __expf(-v));
        Ps[(w * 16 + hi * 4 + r) * 136 + kj * 16 + fr] = f2b(p);
      }
    }
    __syncthreads();
    #pragma unroll
    for (int ks = 0; ks < 4; ++ks) {
      s16x8 pa = *(const s16x8*)&Ps[(w * 16 + fr) * 136 + ks * 32 + hi * 8];
      #pragma unroll
      for (int dn = 0; dn < 4; ++dn) {
        s16x8 vb = *(const s16x8*)&Vs[(dn * 16 + fr) * 136 + ks * 32 + hi * 8];
        acc_o[dn] = MFMA16(pa, vb, acc_o[dn]);
      }
    }
    __syncthreads();
  }
  #pragma unroll
  for (int dn = 0; dn < 4; ++dn) {
    int col = h * TDH + dn * 16 + fr;
    #pragma unroll
    for (int r = 0; r < 4; ++r) {
      size_t row = qrow0 + w * 16 + hi * 4 + r;
      ao[row * TD + col] = acc_o[dn][r] + b2f(xb[row * TD + col]);   // fused residual (bf16 x)
    }
  }
}

// ---------------- K3: LayerNorm over D=512 (TF-style, eps=1e-12), bf16 out ----------------
__global__ __launch_bounds__(256) void k_ln(const float* __restrict__ a, const float* __restrict__ w,
                                            const float* __restrict__ bias, bfu* __restrict__ o) {
  int row = blockIdx.x, t = threadIdx.x;
  float2 v = *(const float2*)(a + (size_t)row * TD + t * 2);
  float s = v.x + v.y;
  #pragma unroll
  for (int off = 32; off > 0; off >>= 1) s += __shfl_down(s, off);
  __shared__ float r1[4], r2[4];
  int lane = t & 63, wv = t >> 6;
  if (lane == 0) r1[wv] = s;
  __syncthreads();
  float mean = (r1[0] + r1[1] + r1[2] + r1[3]) * (1.f / TD);
  float dx = v.x - mean, dy = v.y - mean;
  float q = dx * dx + dy * dy;
  #pragma unroll
  for (int off = 32; off > 0; off >>= 1) q += __shfl_down(q, off);
  if (lane == 0) r2[wv] = q;
  __syncthreads();
  float var = (r2[0] + r2[1] + r2[2] + r2[3]) * (1.f / TD);
  float inv = rsqrtf(var + 1e-12f);
  float2 wv2 = *(const float2*)(w + t * 2);
  float2 bv2 = *(const float2*)(bias + t * 2);
  unsigned pack = (unsigned)f2b(wv2.x * dx * inv + bv2.x) |
                  ((unsigned)f2b(wv2.y * dy * inv + bv2.y) << 16);
  *(unsigned*)(o + (size_t)row * TD + t * 2) = pack;
}

// ---------------- K4: final linear partials ----------------
// grid 1024 = 512 K-chunks x 2 col-halves; block 256 thr; 4 blocks/CU (40KB LDS).
__global__ __launch_bounds__(256) void k_lin_part(const bfu* __restrict__ ln, const float* __restrict__ wl,
                                                  float* __restrict__ part) {
  __shared__ float al[512 * 20];   // [k][16 m + pad4]; b128 uniform reads in main loop
  int t = threadIdx.x;
  int kc = blockIdx.x >> 1;        // 0..511 K-chunk
  int ch = blockIdx.x & 1;         // column half
  int k0 = kc * 512;
  #pragma unroll
  for (int m = 0; m < 16; ++m) {
    al[t * 20 + m]         = b2f(ln[(size_t)m * TSD + k0 + t]);
    al[(256 + t) * 20 + m] = b2f(ln[(size_t)m * TSD + k0 + 256 + t]);
  }
  __syncthreads();
  float acc[16] = {};
  const float* wp = wl + (size_t)k0 * 512 + ch * 256 + t;
  #pragma unroll 8
  for (int k = 0; k < 512; ++k) {
    float wv = __builtin_nontemporal_load(wp + (size_t)k * 512);
    const float* ar = &al[k * 20];
    float4 a0 = *(const float4*)(ar);
    float4 a1 = *(const float4*)(ar + 4);
    float4 a2 = *(const float4*)(ar + 8);
    float4 a3 = *(const float4*)(ar + 12);
    acc[0]  += a0.x * wv; acc[1]  += a0.y * wv; acc[2]  += a0.z * wv; acc[3]  += a0.w * wv;
    acc[4]  += a1.x * wv; acc[5]  += a1.y * wv; acc[6]  += a1.z * wv; acc[7]  += a1.w * wv;
    acc[8]  += a2.x * wv; acc[9]  += a2.y * wv; acc[10] += a2.z * wv; acc[11] += a2.w * wv;
    acc[12] += a3.x * wv; acc[13] += a3.y * wv; acc[14] += a3.z * wv; acc[15] += a3.w * wv;
  }
  #pragma unroll
  for (int m = 0; m < 16; ++m)
    part[(size_t)kc * 8192 + m * 512 + ch * 256 + t] = acc[m];
}

// ---------------- K5a: reduce level 1: 512 chunks -> 8 slices ----------------
__global__ __launch_bounds__(256) void k_lin_red1(const float* __restrict__ part, float* __restrict__ part2) {
  int t = threadIdx.x;
  int cs = blockIdx.x >> 5;        // 0..7 chunk-slice
  int ob = blockIdx.x & 31;        // output group
  int o = ob * 256 + t;
  float s = 0.f;
  #pragma unroll 8
  for (int c = cs * 64; c < cs * 64 + 64; ++c) s += part[(size_t)c * 8192 + o];
  part2[(size_t)cs * 8192 + o] = s;
}

// ---------------- K5b: reduce level 2 + bias + swish ----------------
__global__ __launch_bounds__(256) void k_lin_red2(const float* __restrict__ part2, const float* __restrict__ blin,
                                                  float* __restrict__ out) {
  int o = blockIdx.x * 256 + threadIdx.x;
  float s = 0.f;
  #pragma unroll
  for (int c = 0; c < 8; ++c) s += part2[(size_t)c * 8192 + o];
  float v = s + blin[o & 511];
  out[o] = v / (1.f + __expf(-v));
}

extern "C" void kernel_launch(void* const* d_in, const int* in_sizes, int n_in,
                              void* d_out, int out_size, void* d_ws, size_t ws_size,
                              hipStream_t stream) {
  const float* x   = (const float*)d_in[0];
  const float* WQ  = (const float*)d_in[1];
  const float* WK  = (const float*)d_in[2];
  const float* WV  = (const float*)d_in[3];
  const float* Wl  = (const float*)d_in[4];
  const float* bl  = (const float*)d_in[5];
  const float* lnw = (const float*)d_in[6];
  const float* lnb = (const float*)d_in[7];
  float* out = (float*)d_out;
  char* ws = (char*)d_ws;
  // workspace layout (no aliasing; ~66MB total)
  bfu* xb  = (bfu*)ws;                     // 4,194,304 bf16
  bfu* wt  = xb + 4194304;                 //   786,432 bf16
  bfu* qb  = wt + 786432;                  // 4,194,304 bf16
  bfu* kb  = qb + 4194304;                 // 4,194,304 bf16
  bfu* vtb = kb + 4194304;                 // 4,194,304 bf16
  float* attn  = (float*)(vtb + 4194304);  // 4,194,304 f32
  bfu*   lno   = (bfu*)(attn + 4194304);   // 4,194,304 bf16
  float* part  = (float*)(lno + 4194304);  // 4,194,304 f32
  float* part2 = part + 4194304;           //    65,536 f32

  k_cast_x  <<<4096, 256, 0, stream>>>((const float4*)x, (ushort4*)xb);
  k_prep_w  <<<192, 256, 0, stream>>>(WQ, WK, WV, wt);
  k_qkv     <<<dim3(64, 12), 256, 0, stream>>>(xb, wt, qb, kb, vtb);
  k_attn    <<<dim3(8, 8, 16), 256, 0, stream>>>(qb, kb, vtb, xb, attn);
  k_ln      <<<8192, 256, 0, stream>>>(attn, lnw, lnb, lno);
  k_lin_part<<<1024, 256, 0, stream>>>(lno, Wl, part);
  k_lin_red1<<<256, 256, 0, stream>>>(part, part2);
  k_lin_red2<<<32, 256, 0, stream>>>(part2, bl, out);
}

// Round 3
// 212.403 us; speedup vs baseline: 1.0842x; 1.0102x over previous
//
#include <hip/hip_runtime.h>
#include <cstdint>

#define TB 16
#define TS 512
#define TD 512
#define TH 8
#define TDH 64
#define TSD (TS*TD)   // 262144

typedef __attribute__((ext_vector_type(8))) short s16x8;
typedef __attribute__((ext_vector_type(4))) float f32x4;
typedef unsigned short bfu;

__device__ __forceinline__ unsigned short f2b(float f) {
  unsigned int u = __float_as_uint(f);
  u += 0x7FFFu + ((u >> 16) & 1u);          // RNE to bf16
  return (unsigned short)(u >> 16);
}
__device__ __forceinline__ float b2f(bfu h) {
  return __uint_as_float(((unsigned)h) << 16);
}

__device__ __forceinline__ void gll16(const void* g, void* l) {
  __builtin_amdgcn_global_load_lds((const __attribute__((address_space(1))) void*)g,
                                   (__attribute__((address_space(3))) void*)l, 16, 0, 0);
}

__device__ __forceinline__ f32x4 MFMA16(s16x8 a, s16x8 b, f32x4 c) {
  return __builtin_amdgcn_mfma_f32_16x16x32_bf16(a, b, c, 0, 0, 0);
}

// ---------------- K0a: cast x (fp32 -> bf16) ----------------
__global__ __launch_bounds__(256) void k_cast_x(const float4* __restrict__ x, ushort4* __restrict__ xb) {
  int i = blockIdx.x * 256 + threadIdx.x;
  float4 v = x[i];
  ushort4 o; o.x = f2b(v.x); o.y = f2b(v.y); o.z = f2b(v.z); o.w = f2b(v.w);
  xb[i] = o;
}

// ---------------- K0b: build W^T bf16 [1536][512] ----------------
__global__ __launch_bounds__(256) void k_prep_w(const float* __restrict__ WQ, const float* __restrict__ WK,
                                                const float* __restrict__ WV, bfu* __restrict__ wt) {
  __shared__ float tile[64][65];
  int bk = blockIdx.x & 7;
  int bn = blockIdx.x >> 3;
  const float* W = bn < 8 ? WQ : (bn < 16 ? WK : WV);
  int ncol0 = (bn & 7) * 64;
  int t = threadIdx.x, tx = t & 63, ty = t >> 6;
  #pragma unroll
  for (int i = 0; i < 16; ++i) {
    int kl = i * 4 + ty;
    tile[kl][tx] = W[(size_t)(bk * 64 + kl) * 512 + ncol0 + tx];
  }
  __syncthreads();
  #pragma unroll
  for (int i = 0; i < 16; ++i) {
    int nl = i * 4 + ty;
    wt[(size_t)(bn * 64 + nl) * 512 + bk * 64 + tx] = f2b(tile[tx][nl]);
  }
}

// ---------------- K1: QKV GEMM (m97 structure) ----------------
__global__ __launch_bounds__(256) void k_qkv(const bfu* __restrict__ xb, const bfu* __restrict__ wt,
                                             bfu* __restrict__ qb, bfu* __restrict__ kb, bfu* __restrict__ vtb) {
  __shared__ __align__(16) bfu At[128 * 32];
  __shared__ __align__(16) bfu Bt[128 * 32];
  int t = threadIdx.x, lane = t & 63, w = t >> 6;
  int wr = w >> 1, wc = w & 1;
  int m0 = blockIdx.x * 128, n0 = blockIdx.y * 128;
  int fr = lane & 15, hi = lane >> 4;
  f32x4 acc[4][4] = {};
  for (int k0 = 0; k0 < TD; k0 += 32) {
    #pragma unroll
    for (int i = 0; i < 2; ++i) {
      int base = (i * 4 + w) * 1024;
      int seg  = (i * 4 + w) * 64 + lane;
      int row = seg >> 2, cs = seg & 3;
      gll16(xb + (size_t)(m0 + row) * TD + k0 + cs * 8, (char*)At + base);
      gll16(wt + (size_t)(n0 + row) * TD + k0 + cs * 8, (char*)Bt + base);
    }
    __syncthreads();
    s16x8 a[4], bb[4];
    #pragma unroll
    for (int m = 0; m < 4; ++m) a[m]  = *(const s16x8*)&At[(wr * 64 + m * 16 + fr) * 32 + hi * 8];
    #pragma unroll
    for (int n = 0; n < 4; ++n) bb[n] = *(const s16x8*)&Bt[(wc * 64 + n * 16 + fr) * 32 + hi * 8];
    #pragma unroll
    for (int m = 0; m < 4; ++m)
      #pragma unroll
      for (int n = 0; n < 4; ++n)
        acc[m][n] = MFMA16(a[m], bb[n], acc[m][n]);
    __syncthreads();
  }
  #pragma unroll
  for (int m = 0; m < 4; ++m) {
    int grow = m0 + wr * 64 + m * 16 + hi * 4;
    #pragma unroll
    for (int n = 0; n < 4; ++n) {
      int gcol = n0 + wc * 64 + n * 16 + fr;
      if (gcol < 512) {
        #pragma unroll
        for (int r = 0; r < 4; ++r) qb[(size_t)(grow + r) * TD + gcol] = f2b(acc[m][n][r]);
      } else if (gcol < 1024) {
        int c = gcol - 512;
        #pragma unroll
        for (int r = 0; r < 4; ++r) kb[(size_t)(grow + r) * TD + c] = f2b(acc[m][n][r]);
      } else {
        int c = gcol - 1024;
        int hh = c >> 6, dc = c & 63;
        int b_ = grow >> 9, s = grow & 511;
        ushort4 pk;
        pk.x = f2b(acc[m][n][0]); pk.y = f2b(acc[m][n][1]);
        pk.z = f2b(acc[m][n][2]); pk.w = f2b(acc[m][n][3]);
        *(ushort4*)&vtb[((size_t)((b_ * TH + hh) * TDH + dc) << 9) + s] = pk;
      }
    }
  }
}

// ---------------- K2: attention per (qtile=64, h, b) ----------------
__global__ __launch_bounds__(256) void k_attn(const bfu* __restrict__ qb, const bfu* __restrict__ kb,
                                              const bfu* __restrict__ vtb, const bfu* __restrict__ xb,
                                              float* __restrict__ ao) {
  __shared__ __align__(16) bfu Qs[64 * 72];
  __shared__ __align__(16) bfu Ks[128 * 72];
  __shared__ __align__(16) bfu Vs[64 * 136];   // [dh][keys]
  __shared__ __align__(16) bfu Ps[64 * 136];   // [q][keys] wave-private rows
  int t = threadIdx.x, lane = t & 63, w = t >> 6;
  int qt = blockIdx.x, h = blockIdx.y, b = blockIdx.z;
  size_t qrow0 = (size_t)b * TS + qt * 64;
  int fr = lane & 15, hi = lane >> 4;
  #pragma unroll
  for (int i = 0; i < 2; ++i) {
    int seg = i * 256 + t, row = seg >> 3, cs = seg & 7;
    s16x8 v = *(const s16x8*)(qb + (qrow0 + row) * TD + h * TDH + cs * 8);
    *(s16x8*)&Qs[row * 72 + cs * 8] = v;
  }
  f32x4 acc_o[4] = {};
  for (int kt = 0; kt < 4; ++kt) {
    #pragma unroll
    for (int i = 0; i < 4; ++i) {
      int seg = i * 256 + t, row = seg >> 3, cs = seg & 7;
      s16x8 v = *(const s16x8*)(kb + ((size_t)b * TS + kt * 128 + row) * TD + h * TDH + cs * 8);
      *(s16x8*)&Ks[row * 72 + cs * 8] = v;
    }
    #pragma unroll
    for (int i = 0; i < 4; ++i) {
      int seg = i * 256 + t, row = seg >> 4, cs = seg & 15;
      s16x8 v = *(const s16x8*)(vtb + ((size_t)(b * TH + h) * TDH + row) * TS + kt * 128 + cs * 8);
      *(s16x8*)&Vs[row * 136 + cs * 8] = v;
    }
    __syncthreads();
    s16x8 aq0 = *(const s16x8*)&Qs[(w * 16 + fr) * 72 + hi * 8];
    s16x8 aq1 = *(const s16x8*)&Qs[(w * 16 + fr) * 72 + 32 + hi * 8];
    f32x4 sc[8];
    #pragma unroll
    for (int kj = 0; kj < 8; ++kj) {
      s16x8 b0 = *(const s16x8*)&Ks[(kj * 16 + fr) * 72 + hi * 8];
      s16x8 b1 = *(const s16x8*)&Ks[(kj * 16 + fr) * 72 + 32 + hi * 8];
      f32x4 c = {};
      c = MFMA16(aq0, b0, c);
      c = MFMA16(aq1, b1, c);
      sc[kj] = c;
    }
    #pragma unroll
    for (int kj = 0; kj < 8; ++kj) {
      #pragma unroll
      for (int r = 0; r < 4; ++r) {
        float v = sc[kj][r] * 0.125f;
        float p = v / (1.f + __expf(-v));
        Ps[(w * 16 + hi * 4 + r) * 136 + kj * 16 + fr] = f2b(p);
      }
    }
    // NOTE: no __syncthreads here — P rows are wave-private (writer rows
    // w*16..w*16+15 == reader rows); compiler's lgkmcnt ordering covers the
    // same-wave LDS RAW. Vs/Ks are read-only since the staging barrier.
    #pragma unroll
    for (int ks = 0; ks < 4; ++ks) {
      s16x8 pa = *(const s16x8*)&Ps[(w * 16 + fr) * 136 + ks * 32 + hi * 8];
      #pragma unroll
      for (int dn = 0; dn < 4; ++dn) {
        s16x8 vb = *(const s16x8*)&Vs[(dn * 16 + fr) * 136 + ks * 32 + hi * 8];
        acc_o[dn] = MFMA16(pa, vb, acc_o[dn]);
      }
    }
    __syncthreads();
  }
  #pragma unroll
  for (int dn = 0; dn < 4; ++dn) {
    int col = h * TDH + dn * 16 + fr;
    #pragma unroll
    for (int r = 0; r < 4; ++r) {
      size_t row = qrow0 + w * 16 + hi * 4 + r;
      ao[row * TD + col] = acc_o[dn][r] + b2f(xb[row * TD + col]);
    }
  }
}

// ---------------- K4: fused LayerNorm + linear partials ----------------
// grid 1024 = 512 s-chunks x 2 col-halves. Chunk kc covers flat features
// [kc*512, kc*512+512) = (s=kc, all d) for each of the 16 batch rows -> LN rows.
__global__ __launch_bounds__(256) void k_lin_part(const float* __restrict__ attn, const float* __restrict__ lnw,
                                                  const float* __restrict__ lnb, const float* __restrict__ wl,
                                                  float* __restrict__ part) {
  __shared__ float al[512 * 20];   // [d][16 m + pad4]
  int t = threadIdx.x;
  int kc = blockIdx.x >> 1;        // s position
  int ch = blockIdx.x & 1;         // column half
  int k0 = kc * 512;
  // --- LN: 16 threads per batch row m, each covers 32 d ---
  {
    int m = t >> 4, d0 = (t & 15) * 32;
    const float* row = attn + ((size_t)m * TS + kc) * TD;
    float4 v[8];
    float s = 0.f;
    #pragma unroll
    for (int j = 0; j < 8; ++j) {
      v[j] = *(const float4*)(row + d0 + j * 4);
      s += v[j].x + v[j].y + v[j].z + v[j].w;
    }
    #pragma unroll
    for (int off = 8; off > 0; off >>= 1) s += __shfl_xor(s, off, 16);
    float mean = s * (1.f / 512.f);
    float q = 0.f;
    #pragma unroll
    for (int j = 0; j < 8; ++j) {
      float dx = v[j].x - mean, dy = v[j].y - mean, dz = v[j].z - mean, dw = v[j].w - mean;
      q += dx * dx + dy * dy + dz * dz + dw * dw;
    }
    #pragma unroll
    for (int off = 8; off > 0; off >>= 1) q += __shfl_xor(q, off, 16);
    float inv = rsqrtf(q * (1.f / 512.f) + 1e-12f);
    #pragma unroll
    for (int j = 0; j < 8; ++j) {
      float4 wv = *(const float4*)(lnw + d0 + j * 4);
      float4 bv = *(const float4*)(lnb + d0 + j * 4);
      int d = d0 + j * 4;
      al[(d + 0) * 20 + m] = wv.x * (v[j].x - mean) * inv + bv.x;
      al[(d + 1) * 20 + m] = wv.y * (v[j].y - mean) * inv + bv.y;
      al[(d + 2) * 20 + m] = wv.z * (v[j].z - mean) * inv + bv.z;
      al[(d + 3) * 20 + m] = wv.w * (v[j].w - mean) * inv + bv.w;
    }
  }
  __syncthreads();
  float acc[16] = {};
  const float* wp = wl + (size_t)k0 * 512 + ch * 256 + t;
  #pragma unroll 8
  for (int k = 0; k < 512; ++k) {
    float wv = __builtin_nontemporal_load(wp + (size_t)k * 512);
    const float* ar = &al[k * 20];
    float4 a0 = *(const float4*)(ar);
    float4 a1 = *(const float4*)(ar + 4);
    float4 a2 = *(const float4*)(ar + 8);
    float4 a3 = *(const float4*)(ar + 12);
    acc[0]  += a0.x * wv; acc[1]  += a0.y * wv; acc[2]  += a0.z * wv; acc[3]  += a0.w * wv;
    acc[4]  += a1.x * wv; acc[5]  += a1.y * wv; acc[6]  += a1.z * wv; acc[7]  += a1.w * wv;
    acc[8]  += a2.x * wv; acc[9]  += a2.y * wv; acc[10] += a2.z * wv; acc[11] += a2.w * wv;
    acc[12] += a3.x * wv; acc[13] += a3.y * wv; acc[14] += a3.z * wv; acc[15] += a3.w * wv;
  }
  #pragma unroll
  for (int m = 0; m < 16; ++m)
    part[(size_t)kc * 8192 + m * 512 + ch * 256 + t] = acc[m];
}

// ---------------- K5a: reduce level 1: 512 chunks -> 8 slices ----------------
__global__ __launch_bounds__(256) void k_lin_red1(const float* __restrict__ part, float* __restrict__ part2) {
  int t = threadIdx.x;
  int cs = blockIdx.x >> 5;
  int ob = blockIdx.x & 31;
  int o = ob * 256 + t;
  float s = 0.f;
  #pragma unroll 16
  for (int c = cs * 64; c < cs * 64 + 64; ++c) s += part[(size_t)c * 8192 + o];
  part2[(size_t)cs * 8192 + o] = s;
}

// ---------------- K5b: reduce level 2 + bias + swish ----------------
__global__ __launch_bounds__(256) void k_lin_red2(const float* __restrict__ part2, const float* __restrict__ blin,
                                                  float* __restrict__ out) {
  int o = blockIdx.x * 256 + threadIdx.x;
  float s = 0.f;
  #pragma unroll
  for (int c = 0; c < 8; ++c) s += part2[(size_t)c * 8192 + o];
  float v = s + blin[o & 511];
  out[o] = v / (1.f + __expf(-v));
}

extern "C" void kernel_launch(void* const* d_in, const int* in_sizes, int n_in,
                              void* d_out, int out_size, void* d_ws, size_t ws_size,
                              hipStream_t stream) {
  const float* x   = (const float*)d_in[0];
  const float* WQ  = (const float*)d_in[1];
  const float* WK  = (const float*)d_in[2];
  const float* WV  = (const float*)d_in[3];
  const float* Wl  = (const float*)d_in[4];
  const float* bl  = (const float*)d_in[5];
  const float* lnw = (const float*)d_in[6];
  const float* lnb = (const float*)d_in[7];
  float* out = (float*)d_out;
  char* ws = (char*)d_ws;
  bfu* xb  = (bfu*)ws;                     // 4,194,304 bf16
  bfu* wt  = xb + 4194304;                 //   786,432 bf16
  bfu* qb  = wt + 786432;                  // 4,194,304 bf16
  bfu* kb  = qb + 4194304;                 // 4,194,304 bf16
  bfu* vtb = kb + 4194304;                 // 4,194,304 bf16
  float* attn  = (float*)(vtb + 4194304);  // 4,194,304 f32
  float* part  = attn + 4194304;           // 4,194,304 f32
  float* part2 = part + 4194304;           //    65,536 f32

  k_cast_x  <<<4096, 256, 0, stream>>>((const float4*)x, (ushort4*)xb);
  k_prep_w  <<<192, 256, 0, stream>>>(WQ, WK, WV, wt);
  k_qkv     <<<dim3(64, 12), 256, 0, stream>>>(xb, wt, qb, kb, vtb);
  k_attn    <<<dim3(8, 8, 16), 256, 0, stream>>>(qb, kb, vtb, xb, attn);
  k_lin_part<<<1024, 256, 0, stream>>>(attn, lnw, lnb, Wl, part);
  k_lin_red1<<<256, 256, 0, stream>>>(part, part2);
  k_lin_red2<<<32, 256, 0, stream>>>(part2, bl, out);
}

// Round 4
// 198.929 us; speedup vs baseline: 1.1576x; 1.0677x over previous
//
#include <hip/hip_runtime.h>
#include <cstdint>

#define TB 16
#define TS 512
#define TD 512
#define TH 8
#define TDH 64
#define TSD (TS*TD)   // 262144

typedef __attribute__((ext_vector_type(8))) short s16x8;
typedef __attribute__((ext_vector_type(4))) float f32x4;
typedef unsigned short bfu;

__device__ __forceinline__ unsigned short f2b(float f) {
  unsigned int u = __float_as_uint(f);
  u += 0x7FFFu + ((u >> 16) & 1u);          // RNE to bf16
  return (unsigned short)(u >> 16);
}
__device__ __forceinline__ float b2f(bfu h) {
  return __uint_as_float(((unsigned)h) << 16);
}

__device__ __forceinline__ void gll16(const void* g, void* l) {
  __builtin_amdgcn_global_load_lds((const __attribute__((address_space(1))) void*)g,
                                   (__attribute__((address_space(3))) void*)l, 16, 0, 0);
}

__device__ __forceinline__ f32x4 MFMA16(s16x8 a, s16x8 b, f32x4 c) {
  return __builtin_amdgcn_mfma_f32_16x16x32_bf16(a, b, c, 0, 0, 0);
}

// ---------------- K0a: cast x (fp32 -> bf16) ----------------
__global__ __launch_bounds__(256) void k_cast_x(const float4* __restrict__ x, ushort4* __restrict__ xb) {
  int i = blockIdx.x * 256 + threadIdx.x;
  float4 v = x[i];
  ushort4 o; o.x = f2b(v.x); o.y = f2b(v.y); o.z = f2b(v.z); o.w = f2b(v.w);
  xb[i] = o;
}

// ---------------- K0b: build W^T bf16 [1536][512] ----------------
__global__ __launch_bounds__(256) void k_prep_w(const float* __restrict__ WQ, const float* __restrict__ WK,
                                                const float* __restrict__ WV, bfu* __restrict__ wt) {
  __shared__ float tile[64][65];
  int bk = blockIdx.x & 7;
  int bn = blockIdx.x >> 3;
  const float* W = bn < 8 ? WQ : (bn < 16 ? WK : WV);
  int ncol0 = (bn & 7) * 64;
  int t = threadIdx.x, tx = t & 63, ty = t >> 6;
  #pragma unroll
  for (int i = 0; i < 16; ++i) {
    int kl = i * 4 + ty;
    tile[kl][tx] = W[(size_t)(bk * 64 + kl) * 512 + ncol0 + tx];
  }
  __syncthreads();
  #pragma unroll
  for (int i = 0; i < 16; ++i) {
    int nl = i * 4 + ty;
    wt[(size_t)(bn * 64 + nl) * 512 + bk * 64 + tx] = f2b(tile[tx][nl]);
  }
}

// ---------------- K1: QKV GEMM (m97 structure) ----------------
__global__ __launch_bounds__(256) void k_qkv(const bfu* __restrict__ xb, const bfu* __restrict__ wt,
                                             bfu* __restrict__ qb, bfu* __restrict__ kb, bfu* __restrict__ vtb) {
  __shared__ __align__(16) bfu At[128 * 32];
  __shared__ __align__(16) bfu Bt[128 * 32];
  int t = threadIdx.x, lane = t & 63, w = t >> 6;
  int wr = w >> 1, wc = w & 1;
  int m0 = blockIdx.x * 128, n0 = blockIdx.y * 128;
  int fr = lane & 15, hi = lane >> 4;
  f32x4 acc[4][4] = {};
  for (int k0 = 0; k0 < TD; k0 += 32) {
    #pragma unroll
    for (int i = 0; i < 2; ++i) {
      int base = (i * 4 + w) * 1024;
      int seg  = (i * 4 + w) * 64 + lane;
      int row = seg >> 2, cs = seg & 3;
      gll16(xb + (size_t)(m0 + row) * TD + k0 + cs * 8, (char*)At + base);
      gll16(wt + (size_t)(n0 + row) * TD + k0 + cs * 8, (char*)Bt + base);
    }
    __syncthreads();
    s16x8 a[4], bb[4];
    #pragma unroll
    for (int m = 0; m < 4; ++m) a[m]  = *(const s16x8*)&At[(wr * 64 + m * 16 + fr) * 32 + hi * 8];
    #pragma unroll
    for (int n = 0; n < 4; ++n) bb[n] = *(const s16x8*)&Bt[(wc * 64 + n * 16 + fr) * 32 + hi * 8];
    #pragma unroll
    for (int m = 0; m < 4; ++m)
      #pragma unroll
      for (int n = 0; n < 4; ++n)
        acc[m][n] = MFMA16(a[m], bb[n], acc[m][n]);
    __syncthreads();
  }
  #pragma unroll
  for (int m = 0; m < 4; ++m) {
    int grow = m0 + wr * 64 + m * 16 + hi * 4;
    #pragma unroll
    for (int n = 0; n < 4; ++n) {
      int gcol = n0 + wc * 64 + n * 16 + fr;
      if (gcol < 512) {
        #pragma unroll
        for (int r = 0; r < 4; ++r) qb[(size_t)(grow + r) * TD + gcol] = f2b(acc[m][n][r]);
      } else if (gcol < 1024) {
        int c = gcol - 512;
        #pragma unroll
        for (int r = 0; r < 4; ++r) kb[(size_t)(grow + r) * TD + c] = f2b(acc[m][n][r]);
      } else {
        int c = gcol - 1024;
        int hh = c >> 6, dc = c & 63;
        int b_ = grow >> 9, s = grow & 511;
        ushort4 pk;
        pk.x = f2b(acc[m][n][0]); pk.y = f2b(acc[m][n][1]);
        pk.z = f2b(acc[m][n][2]); pk.w = f2b(acc[m][n][3]);
        *(ushort4*)&vtb[((size_t)((b_ * TH + hh) * TDH + dc) << 9) + s] = pk;
      }
    }
  }
}

// ---------------- K2: attention per (qtile=64, h, b) ----------------
__global__ __launch_bounds__(256) void k_attn(const bfu* __restrict__ qb, const bfu* __restrict__ kb,
                                              const bfu* __restrict__ vtb, const bfu* __restrict__ xb,
                                              float* __restrict__ ao) {
  __shared__ __align__(16) bfu Qs[64 * 72];
  __shared__ __align__(16) bfu Ks[128 * 72];
  __shared__ __align__(16) bfu Vs[64 * 136];   // [dh][keys]
  __shared__ __align__(16) bfu Ps[64 * 136];   // [q][keys] wave-private rows
  int t = threadIdx.x, lane = t & 63, w = t >> 6;
  int qt = blockIdx.x, h = blockIdx.y, b = blockIdx.z;
  size_t qrow0 = (size_t)b * TS + qt * 64;
  int fr = lane & 15, hi = lane >> 4;
  #pragma unroll
  for (int i = 0; i < 2; ++i) {
    int seg = i * 256 + t, row = seg >> 3, cs = seg & 7;
    s16x8 v = *(const s16x8*)(qb + (qrow0 + row) * TD + h * TDH + cs * 8);
    *(s16x8*)&Qs[row * 72 + cs * 8] = v;
  }
  f32x4 acc_o[4] = {};
  for (int kt = 0; kt < 4; ++kt) {
    #pragma unroll
    for (int i = 0; i < 4; ++i) {
      int seg = i * 256 + t, row = seg >> 3, cs = seg & 7;
      s16x8 v = *(const s16x8*)(kb + ((size_t)b * TS + kt * 128 + row) * TD + h * TDH + cs * 8);
      *(s16x8*)&Ks[row * 72 + cs * 8] = v;
    }
    #pragma unroll
    for (int i = 0; i < 4; ++i) {
      int seg = i * 256 + t, row = seg >> 4, cs = seg & 15;
      s16x8 v = *(const s16x8*)(vtb + ((size_t)(b * TH + h) * TDH + row) * TS + kt * 128 + cs * 8);
      *(s16x8*)&Vs[row * 136 + cs * 8] = v;
    }
    __syncthreads();
    s16x8 aq0 = *(const s16x8*)&Qs[(w * 16 + fr) * 72 + hi * 8];
    s16x8 aq1 = *(const s16x8*)&Qs[(w * 16 + fr) * 72 + 32 + hi * 8];
    f32x4 sc[8];
    #pragma unroll
    for (int kj = 0; kj < 8; ++kj) {
      s16x8 b0 = *(const s16x8*)&Ks[(kj * 16 + fr) * 72 + hi * 8];
      s16x8 b1 = *(const s16x8*)&Ks[(kj * 16 + fr) * 72 + 32 + hi * 8];
      f32x4 c = {};
      c = MFMA16(aq0, b0, c);
      c = MFMA16(aq1, b1, c);
      sc[kj] = c;
    }
    #pragma unroll
    for (int kj = 0; kj < 8; ++kj) {
      #pragma unroll
      for (int r = 0; r < 4; ++r) {
        float v = sc[kj][r] * 0.125f;
        float p = v / (1.f + __expf(-v));
        Ps[(w * 16 + hi * 4 + r) * 136 + kj * 16 + fr] = f2b(p);
      }
    }
    // P rows are wave-private; same-wave LDS RAW covered by lgkmcnt.
    #pragma unroll
    for (int ks = 0; ks < 4; ++ks) {
      s16x8 pa = *(const s16x8*)&Ps[(w * 16 + fr) * 136 + ks * 32 + hi * 8];
      #pragma unroll
      for (int dn = 0; dn < 4; ++dn) {
        s16x8 vb = *(const s16x8*)&Vs[(dn * 16 + fr) * 136 + ks * 32 + hi * 8];
        acc_o[dn] = MFMA16(pa, vb, acc_o[dn]);
      }
    }
    __syncthreads();
  }
  #pragma unroll
  for (int dn = 0; dn < 4; ++dn) {
    int col = h * TDH + dn * 16 + fr;
    #pragma unroll
    for (int r = 0; r < 4; ++r) {
      size_t row = qrow0 + w * 16 + hi * 4 + r;
      ao[row * TD + col] = acc_o[dn][r] + b2f(xb[row * TD + col]);
    }
  }
}

// ---------------- K3: LayerNorm over D=512, bf16 out ----------------
__global__ __launch_bounds__(256) void k_ln(const float* __restrict__ a, const float* __restrict__ w,
                                            const float* __restrict__ bias, bfu* __restrict__ o) {
  int row = blockIdx.x, t = threadIdx.x;
  float2 v = *(const float2*)(a + (size_t)row * TD + t * 2);
  float s = v.x + v.y;
  #pragma unroll
  for (int off = 32; off > 0; off >>= 1) s += __shfl_down(s, off);
  __shared__ float r1[4], r2[4];
  int lane = t & 63, wv = t >> 6;
  if (lane == 0) r1[wv] = s;
  __syncthreads();
  float mean = (r1[0] + r1[1] + r1[2] + r1[3]) * (1.f / TD);
  float dx = v.x - mean, dy = v.y - mean;
  float q = dx * dx + dy * dy;
  #pragma unroll
  for (int off = 32; off > 0; off >>= 1) q += __shfl_down(q, off);
  if (lane == 0) r2[wv] = q;
  __syncthreads();
  float var = (r2[0] + r2[1] + r2[2] + r2[3]) * (1.f / TD);
  float inv = rsqrtf(var + 1e-12f);
  float2 wv2 = *(const float2*)(w + t * 2);
  float2 bv2 = *(const float2*)(bias + t * 2);
  unsigned pack = (unsigned)f2b(wv2.x * dx * inv + bv2.x) |
                  ((unsigned)f2b(wv2.y * dy * inv + bv2.y) << 16);
  *(unsigned*)(o + (size_t)row * TD + t * 2) = pack;
}

// ---------------- K4: final linear via MFMA ----------------
// grid 1024 = 128 kc-chunks (KC=2048) x 8 n-blocks (64 n each; 4 waves x 16 n).
// Per 64-k step: W[64k][64n] fp32 coalesced -> regs -> bf16 -> LDS [n][72k pad];
// A-frags (lno bf16) per-lane global (L1/LLC-hot); 2 MFMA/wave/step, f32 acc.
// Reg-staged ping-pong: next step's W+A loads issue between LDS-write and MFMA.
__global__ __launch_bounds__(256) void k_lin_mfma(const bfu* __restrict__ lno, const float* __restrict__ wl,
                                                  float* __restrict__ part) {
  __shared__ __align__(16) bfu Wt[64 * 72];
  int t = threadIdx.x, lane = t & 63, w = t >> 6;
  int fr = lane & 15, hi = lane >> 4;
  int kc = blockIdx.x >> 3, nb = blockIdx.x & 7;
  int n0 = nb * 64;
  int nl = t & 63, kb = (t >> 6) * 16;
  int ks0 = kc * 2048;
  const float* wbase = wl + (size_t)(ks0 + kb) * 512 + n0 + nl;
  const bfu*   abase = lno + (size_t)fr * TSD + ks0 + hi * 8;
  f32x4 acc = {};
  float wA[16], wB[16];
  s16x8 aA0, aA1, aB0, aB1;
  #pragma unroll
  for (int i = 0; i < 16; ++i) wA[i] = __builtin_nontemporal_load(wbase + (size_t)i * 512);
  aA0 = *(const s16x8*)abase;
  aA1 = *(const s16x8*)(abase + 32);

#define LIN_STEP(CW, CA0, CA1, NW, NA0, NA1, S)                                   \
  { if (S) __syncthreads();                                                       \
    unsigned pk[8];                                                               \
    _Pragma("unroll")                                                             \
    for (int i = 0; i < 8; ++i)                                                   \
      pk[i] = (unsigned)f2b(CW[2*i]) | ((unsigned)f2b(CW[2*i+1]) << 16);          \
    *(uint4*)&Wt[nl * 72 + kb]     = *(uint4*)&pk[0];                             \
    *(uint4*)&Wt[nl * 72 + kb + 8] = *(uint4*)&pk[4];                             \
    if ((S) + 1 < 32) {                                                           \
      const float* wp2 = wbase + (size_t)((S) + 1) * 64 * 512;                    \
      _Pragma("unroll")                                                           \
      for (int i = 0; i < 16; ++i) NW[i] = __builtin_nontemporal_load(wp2 + (size_t)i * 512); \
      const bfu* ap2 = abase + ((S) + 1) * 64;                                    \
      NA0 = *(const s16x8*)ap2; NA1 = *(const s16x8*)(ap2 + 32);                  \
    }                                                                             \
    __syncthreads();                                                              \
    s16x8 b0 = *(const s16x8*)&Wt[(w * 16 + fr) * 72 + hi * 8];                   \
    s16x8 b1 = *(const s16x8*)&Wt[(w * 16 + fr) * 72 + 32 + hi * 8];              \
    acc = MFMA16(CA0, b0, acc);                                                   \
    acc = MFMA16(CA1, b1, acc); }

  for (int s = 0; s < 32; s += 2) {
    LIN_STEP(wA, aA0, aA1, wB, aB0, aB1, s)
    LIN_STEP(wB, aB0, aB1, wA, aA0, aA1, s + 1)
  }
#undef LIN_STEP
  // D row (batch m) = hi*4+r, col (n) = fr
  #pragma unroll
  for (int r = 0; r < 4; ++r)
    part[(size_t)kc * 8192 + (hi * 4 + r) * 512 + n0 + w * 16 + fr] = acc[r];
}

// ---------------- K5: reduce 128 partials + bias + swish ----------------
__global__ __launch_bounds__(256) void k_lin_red(const float* __restrict__ part, const float* __restrict__ blin,
                                                 float* __restrict__ out) {
  int o = blockIdx.x * 256 + threadIdx.x;   // 8192 outputs
  float s = 0.f;
  #pragma unroll 16
  for (int c = 0; c < 128; ++c) s += part[(size_t)c * 8192 + o];
  float v = s + blin[o & 511];
  out[o] = v / (1.f + __expf(-v));
}

extern "C" void kernel_launch(void* const* d_in, const int* in_sizes, int n_in,
                              void* d_out, int out_size, void* d_ws, size_t ws_size,
                              hipStream_t stream) {
  const float* x   = (const float*)d_in[0];
  const float* WQ  = (const float*)d_in[1];
  const float* WK  = (const float*)d_in[2];
  const float* WV  = (const float*)d_in[3];
  const float* Wl  = (const float*)d_in[4];
  const float* bl  = (const float*)d_in[5];
  const float* lnw = (const float*)d_in[6];
  const float* lnb = (const float*)d_in[7];
  float* out = (float*)d_out;
  char* ws = (char*)d_ws;
  bfu* xb  = (bfu*)ws;                     // 4,194,304 bf16
  bfu* wt  = xb + 4194304;                 //   786,432 bf16
  bfu* qb  = wt + 786432;                  // 4,194,304 bf16
  bfu* kb  = qb + 4194304;                 // 4,194,304 bf16
  bfu* vtb = kb + 4194304;                 // 4,194,304 bf16
  float* attn = (float*)(vtb + 4194304);   // 4,194,304 f32
  bfu*   lno  = (bfu*)(attn + 4194304);    // 4,194,304 bf16
  float* part = (float*)(lno + 4194304);   // 1,048,576 f32
  float* pend = part + 1048576;            // (end)
  (void)pend; (void)ws_size;

  k_cast_x  <<<4096, 256, 0, stream>>>((const float4*)x, (ushort4*)xb);
  k_prep_w  <<<192, 256, 0, stream>>>(WQ, WK, WV, wt);
  k_qkv     <<<dim3(64, 12), 256, 0, stream>>>(xb, wt, qb, kb, vtb);
  k_attn    <<<dim3(8, 8, 16), 256, 0, stream>>>(qb, kb, vtb, xb, attn);
  k_ln      <<<8192, 256, 0, stream>>>(attn, lnw, lnb, lno);
  k_lin_mfma<<<1024, 256, 0, stream>>>(lno, Wl, part);
  k_lin_red <<<32, 256, 0, stream>>>(part, bl, out);
}

// Round 5
// 185.694 us; speedup vs baseline: 1.2402x; 1.0713x over previous
//
#include <hip/hip_runtime.h>
#include <cstdint>

#define TB 16
#define TS 512
#define TD 512
#define TH 8
#define TDH 64
#define TSD (TS*TD)   // 262144

typedef __attribute__((ext_vector_type(8))) short s16x8;
typedef __attribute__((ext_vector_type(4))) float f32x4;
typedef unsigned short bfu;

__device__ __forceinline__ unsigned short f2b(float f) {
  unsigned int u = __float_as_uint(f);
  u += 0x7FFFu + ((u >> 16) & 1u);          // RNE to bf16
  return (unsigned short)(u >> 16);
}
__device__ __forceinline__ float b2f(bfu h) {
  return __uint_as_float(((unsigned)h) << 16);
}

__device__ __forceinline__ void gll16(const void* g, void* l) {
  __builtin_amdgcn_global_load_lds((const __attribute__((address_space(1))) void*)g,
                                   (__attribute__((address_space(3))) void*)l, 16, 0, 0);
}

__device__ __forceinline__ f32x4 MFMA16(s16x8 a, s16x8 b, f32x4 c) {
  return __builtin_amdgcn_mfma_f32_16x16x32_bf16(a, b, c, 0, 0, 0);
}

// ---------------- K0: fused cast x (fp32->bf16) + build W^T bf16 [1536][512] ----------------
__global__ __launch_bounds__(256) void k_prep(const float* __restrict__ x, ushort4* __restrict__ xb,
                                              const float* __restrict__ WQ, const float* __restrict__ WK,
                                              const float* __restrict__ WV, bfu* __restrict__ wt) {
  int t = threadIdx.x;
  if (blockIdx.x < 4096) {
    int i = blockIdx.x * 256 + t;
    float4 v = ((const float4*)x)[i];
    ushort4 o; o.x = f2b(v.x); o.y = f2b(v.y); o.z = f2b(v.z); o.w = f2b(v.w);
    xb[i] = o;
    return;
  }
  __shared__ float tile[64][65];
  int bid = blockIdx.x - 4096;
  int bk = bid & 7;
  int bn = bid >> 3;
  const float* W = bn < 8 ? WQ : (bn < 16 ? WK : WV);
  int ncol0 = (bn & 7) * 64;
  int tx = t & 63, ty = t >> 6;
  #pragma unroll
  for (int i = 0; i < 16; ++i) {
    int kl = i * 4 + ty;
    tile[kl][tx] = W[(size_t)(bk * 64 + kl) * 512 + ncol0 + tx];
  }
  __syncthreads();
  #pragma unroll
  for (int i = 0; i < 16; ++i) {
    int nl = i * 4 + ty;
    wt[(size_t)(bn * 64 + nl) * 512 + bk * 64 + tx] = f2b(tile[tx][nl]);
  }
}

// ---------------- K1: QKV GEMM — 2-phase dbuf + XOR-swizzled LDS ----------------
// C[m][n] = sum_k xb[m][k] wt[n][k]; tiles 128x128, BK=32, gll16 with pre-swizzled source.
__global__ __launch_bounds__(256) void k_qkv(const bfu* __restrict__ xb, const bfu* __restrict__ wt,
                                             bfu* __restrict__ qb, bfu* __restrict__ kb, bfu* __restrict__ vtb) {
  __shared__ __align__(16) bfu At[2][128 * 32];
  __shared__ __align__(16) bfu Bt[2][128 * 32];
  int t = threadIdx.x, lane = t & 63, w = t >> 6;
  int wr = w >> 1, wc = w & 1;
  int m0 = blockIdx.x * 128, n0 = blockIdx.y * 128;
  int fr = lane & 15, hi = lane >> 4;
  int l4r = lane >> 2, l4c = lane & 3;    // 4x16B chunks per 32-elem row
  f32x4 acc[4][4] = {};

#define QKV_STAGE(BUF, K0) { \
    _Pragma("unroll") \
    for (int i = 0; i < 2; ++i) { \
      int row = i * 64 + w * 16 + l4r; \
      int cs = l4c ^ (l4r & 3);                        /* row&3 == l4r&3 */ \
      gll16(xb + (size_t)(m0 + row) * TD + (K0) + cs * 8, (char*)At[BUF] + (i * 256 + w * 64) * 16); \
      gll16(wt + (size_t)(n0 + row) * TD + (K0) + cs * 8, (char*)Bt[BUF] + (i * 256 + w * 64) * 16); \
    } }

#define QKV_COMP(BUF) { \
    s16x8 a[4], bb[4]; \
    int ca = (hi ^ (fr & 3)) * 8; \
    _Pragma("unroll") \
    for (int m = 0; m < 4; ++m) a[m]  = *(const s16x8*)&At[BUF][(wr * 64 + m * 16 + fr) * 32 + ca]; \
    _Pragma("unroll") \
    for (int n = 0; n < 4; ++n) bb[n] = *(const s16x8*)&Bt[BUF][(wc * 64 + n * 16 + fr) * 32 + ca]; \
    _Pragma("unroll") \
    for (int m = 0; m < 4; ++m) \
      _Pragma("unroll") \
      for (int n = 0; n < 4; ++n) \
        acc[m][n] = MFMA16(a[m], bb[n], acc[m][n]); }

  QKV_STAGE(0, 0)
  __syncthreads();
  for (int k = 0; k < 16; ++k) {
    int cur = k & 1;
    if (k < 15) QKV_STAGE(cur ^ 1, (k + 1) * 32)
    QKV_COMP(cur)
    __syncthreads();   // drains prefetch gll + guards buffer reuse (one barrier/step)
  }
#undef QKV_STAGE
#undef QKV_COMP

  #pragma unroll
  for (int m = 0; m < 4; ++m) {
    int grow = m0 + wr * 64 + m * 16 + hi * 4;
    #pragma unroll
    for (int n = 0; n < 4; ++n) {
      int gcol = n0 + wc * 64 + n * 16 + fr;
      if (gcol < 512) {
        #pragma unroll
        for (int r = 0; r < 4; ++r) qb[(size_t)(grow + r) * TD + gcol] = f2b(acc[m][n][r]);
      } else if (gcol < 1024) {
        int c = gcol - 512;
        #pragma unroll
        for (int r = 0; r < 4; ++r) kb[(size_t)(grow + r) * TD + c] = f2b(acc[m][n][r]);
      } else {
        int c = gcol - 1024;
        int hh = c >> 6, dc = c & 63;
        int b_ = grow >> 9, s = grow & 511;
        ushort4 pk;
        pk.x = f2b(acc[m][n][0]); pk.y = f2b(acc[m][n][1]);
        pk.z = f2b(acc[m][n][2]); pk.w = f2b(acc[m][n][3]);
        *(ushort4*)&vtb[((size_t)((b_ * TH + hh) * TDH + dc) << 9) + s] = pk;
      }
    }
  }
}

// ---------------- K2: attention per (qtile=64, h, b) — XOR-swizzled LDS, gll staging ----------------
__global__ __launch_bounds__(256) void k_attn(const bfu* __restrict__ qb, const bfu* __restrict__ kb,
                                              const bfu* __restrict__ vtb, const bfu* __restrict__ xb,
                                              float* __restrict__ ao) {
  __shared__ __align__(16) bfu Qs[64 * 64];    // [q][d]  8x16B chunks/row, chunk^=(row&7)
  __shared__ __align__(16) bfu Ks[128 * 64];   // [k][d]
  __shared__ __align__(16) bfu Vs[64 * 128];   // [d][key] 16 chunks/row, chunk^=(row&7)
  __shared__ __align__(16) bfu Ps[64 * 128];   // [q][key] wave-private rows
  int t = threadIdx.x, lane = t & 63, w = t >> 6;
  int qt = blockIdx.x, h = blockIdx.y, b = blockIdx.z;
  size_t qrow0 = (size_t)b * TS + qt * 64;
  int fr = lane & 15, hi = lane >> 4;
  int l8r = lane >> 3, l8c = lane & 7;
  int l16r = lane >> 4, l16c = lane & 15;

#define K_STAGE(KT) { \
    _Pragma("unroll") \
    for (int i = 0; i < 4; ++i) { \
      int row = i * 32 + w * 8 + l8r; \
      int cs = l8c ^ (l8r & 7);                        /* row&7 == l8r */ \
      gll16(kb + ((size_t)b * TS + (KT) * 128 + row) * TD + h * TDH + cs * 8, \
            (char*)Ks + (i * 256 + w * 64) * 16); \
    } }
#define V_STAGE(KT) { \
    _Pragma("unroll") \
    for (int i = 0; i < 4; ++i) { \
      int row = i * 16 + w * 4 + l16r; \
      int cs = l16c ^ (row & 7); \
      gll16(vtb + ((size_t)(b * TH + h) * TDH + row) * TS + (KT) * 128 + cs * 8, \
            (char*)Vs + (i * 256 + w * 64) * 16); \
    } }

  // Q stage (once) + K/V for kt=0
  #pragma unroll
  for (int i = 0; i < 2; ++i) {
    int row = i * 32 + w * 8 + l8r;
    int cs = l8c ^ (l8r & 7);
    gll16(qb + (qrow0 + row) * TD + h * TDH + cs * 8, (char*)Qs + (i * 256 + w * 64) * 16);
  }
  K_STAGE(0)
  V_STAGE(0)
  __syncthreads();

  int qrow = w * 16 + fr;
  int r7 = fr & 7;
  f32x4 acc_o[4] = {};
  for (int kt = 0; kt < 4; ++kt) {
    s16x8 aq0 = *(const s16x8*)&Qs[qrow * 64 + ((hi ^ r7) * 8)];
    s16x8 aq1 = *(const s16x8*)&Qs[qrow * 64 + (((4 + hi) ^ r7) * 8)];
    f32x4 sc[8];
    #pragma unroll
    for (int kj = 0; kj < 8; ++kj) {
      int krow = kj * 16 + fr;
      s16x8 b0 = *(const s16x8*)&Ks[krow * 64 + ((hi ^ r7) * 8)];
      s16x8 b1 = *(const s16x8*)&Ks[krow * 64 + (((4 + hi) ^ r7) * 8)];
      f32x4 c = {};
      c = MFMA16(aq0, b0, c);
      c = MFMA16(aq1, b1, c);
      sc[kj] = c;
    }
    #pragma unroll
    for (int kj = 0; kj < 8; ++kj) {
      #pragma unroll
      for (int r = 0; r < 4; ++r) {
        float v = sc[kj][r] * 0.125f;
        float p = v / (1.f + __expf(-v));
        int prow = w * 16 + hi * 4 + r;
        int c8 = (kj * 2 + (fr >> 3)) ^ (prow & 7);
        Ps[prow * 128 + c8 * 8 + (fr & 7)] = f2b(p);
      }
    }
    // P rows wave-private: same-wave LDS RAW covered by lgkmcnt; no barrier.
    #pragma unroll
    for (int ks = 0; ks < 4; ++ks) {
      s16x8 pa = *(const s16x8*)&Ps[qrow * 128 + (((ks * 4 + hi) ^ r7) * 8)];
      #pragma unroll
      for (int dn = 0; dn < 4; ++dn) {
        s16x8 vb = *(const s16x8*)&Vs[(dn * 16 + fr) * 128 + (((ks * 4 + hi) ^ r7) * 8)];
        acc_o[dn] = MFMA16(pa, vb, acc_o[dn]);
      }
    }
    __syncthreads();           // all reads done before restage
    if (kt < 3) {
      K_STAGE(kt + 1)
      V_STAGE(kt + 1)
      __syncthreads();         // staged tiles ready
    }
  }
#undef K_STAGE
#undef V_STAGE
  #pragma unroll
  for (int dn = 0; dn < 4; ++dn) {
    int col = h * TDH + dn * 16 + fr;
    #pragma unroll
    for (int r = 0; r < 4; ++r) {
      size_t row = qrow0 + w * 16 + hi * 4 + r;
      ao[row * TD + col] = acc_o[dn][r] + b2f(xb[row * TD + col]);
    }
  }
}

// ---------------- K3: LayerNorm over D=512, bf16 out ----------------
__global__ __launch_bounds__(256) void k_ln(const float* __restrict__ a, const float* __restrict__ w,
                                            const float* __restrict__ bias, bfu* __restrict__ o) {
  int row = blockIdx.x, t = threadIdx.x;
  float2 v = *(const float2*)(a + (size_t)row * TD + t * 2);
  float s = v.x + v.y;
  #pragma unroll
  for (int off = 32; off > 0; off >>= 1) s += __shfl_down(s, off);
  __shared__ float r1[4], r2[4];
  int lane = t & 63, wv = t >> 6;
  if (lane == 0) r1[wv] = s;
  __syncthreads();
  float mean = (r1[0] + r1[1] + r1[2] + r1[3]) * (1.f / TD);
  float dx = v.x - mean, dy = v.y - mean;
  float q = dx * dx + dy * dy;
  #pragma unroll
  for (int off = 32; off > 0; off >>= 1) q += __shfl_down(q, off);
  if (lane == 0) r2[wv] = q;
  __syncthreads();
  float var = (r2[0] + r2[1] + r2[2] + r2[3]) * (1.f / TD);
  float inv = rsqrtf(var + 1e-12f);
  float2 wv2 = *(const float2*)(w + t * 2);
  float2 bv2 = *(const float2*)(bias + t * 2);
  unsigned pack = (unsigned)f2b(wv2.x * dx * inv + bv2.x) |
                  ((unsigned)f2b(wv2.y * dy * inv + bv2.y) << 16);
  *(unsigned*)(o + (size_t)row * TD + t * 2) = pack;
}

// ---------------- K4: final linear via MFMA ----------------
__global__ __launch_bounds__(256) void k_lin_mfma(const bfu* __restrict__ lno, const float* __restrict__ wl,
                                                  float* __restrict__ part) {
  __shared__ __align__(16) bfu Wt[64 * 72];
  int t = threadIdx.x, lane = t & 63, w = t >> 6;
  int fr = lane & 15, hi = lane >> 4;
  int kc = blockIdx.x >> 3, nb = blockIdx.x & 7;
  int n0 = nb * 64;
  int nl = t & 63, kb = (t >> 6) * 16;
  int ks0 = kc * 2048;
  const float* wbase = wl + (size_t)(ks0 + kb) * 512 + n0 + nl;
  const bfu*   abase = lno + (size_t)fr * TSD + ks0 + hi * 8;
  f32x4 acc = {};
  float wA[16], wB[16];
  s16x8 aA0, aA1, aB0, aB1;
  #pragma unroll
  for (int i = 0; i < 16; ++i) wA[i] = __builtin_nontemporal_load(wbase + (size_t)i * 512);
  aA0 = *(const s16x8*)abase;
  aA1 = *(const s16x8*)(abase + 32);

#define LIN_STEP(CW, CA0, CA1, NW, NA0, NA1, S)                                   \
  { if (S) __syncthreads();                                                       \
    unsigned pk[8];                                                               \
    _Pragma("unroll")                                                             \
    for (int i = 0; i < 8; ++i)                                                   \
      pk[i] = (unsigned)f2b(CW[2*i]) | ((unsigned)f2b(CW[2*i+1]) << 16);          \
    *(uint4*)&Wt[nl * 72 + kb]     = *(uint4*)&pk[0];                             \
    *(uint4*)&Wt[nl * 72 + kb + 8] = *(uint4*)&pk[4];                             \
    if ((S) + 1 < 32) {                                                           \
      const float* wp2 = wbase + (size_t)((S) + 1) * 64 * 512;                    \
      _Pragma("unroll")                                                           \
      for (int i = 0; i < 16; ++i) NW[i] = __builtin_nontemporal_load(wp2 + (size_t)i * 512); \
      const bfu* ap2 = abase + ((S) + 1) * 64;                                    \
      NA0 = *(const s16x8*)ap2; NA1 = *(const s16x8*)(ap2 + 32);                  \
    }                                                                             \
    __syncthreads();                                                              \
    s16x8 b0 = *(const s16x8*)&Wt[(w * 16 + fr) * 72 + hi * 8];                   \
    s16x8 b1 = *(const s16x8*)&Wt[(w * 16 + fr) * 72 + 32 + hi * 8];              \
    acc = MFMA16(CA0, b0, acc);                                                   \
    acc = MFMA16(CA1, b1, acc); }

  for (int s = 0; s < 32; s += 2) {
    LIN_STEP(wA, aA0, aA1, wB, aB0, aB1, s)
    LIN_STEP(wB, aB0, aB1, wA, aA0, aA1, s + 1)
  }
#undef LIN_STEP
  #pragma unroll
  for (int r = 0; r < 4; ++r)
    part[(size_t)kc * 8192 + (hi * 4 + r) * 512 + n0 + w * 16 + fr] = acc[r];
}

// ---------------- K5: reduce 128 partials + bias + swish ----------------
__global__ __launch_bounds__(256) void k_lin_red(const float* __restrict__ part, const float* __restrict__ blin,
                                                 float* __restrict__ out) {
  int o = blockIdx.x * 256 + threadIdx.x;
  float s = 0.f;
  #pragma unroll 16
  for (int c = 0; c < 128; ++c) s += part[(size_t)c * 8192 + o];
  float v = s + blin[o & 511];
  out[o] = v / (1.f + __expf(-v));
}

extern "C" void kernel_launch(void* const* d_in, const int* in_sizes, int n_in,
                              void* d_out, int out_size, void* d_ws, size_t ws_size,
                              hipStream_t stream) {
  const float* x   = (const float*)d_in[0];
  const float* WQ  = (const float*)d_in[1];
  const float* WK  = (const float*)d_in[2];
  const float* WV  = (const float*)d_in[3];
  const float* Wl  = (const float*)d_in[4];
  const float* bl  = (const float*)d_in[5];
  const float* lnw = (const float*)d_in[6];
  const float* lnb = (const float*)d_in[7];
  float* out = (float*)d_out;
  char* ws = (char*)d_ws;
  bfu* xb  = (bfu*)ws;                     // 4,194,304 bf16
  bfu* wt  = xb + 4194304;                 //   786,432 bf16
  bfu* qb  = wt + 786432;                  // 4,194,304 bf16
  bfu* kb  = qb + 4194304;                 // 4,194,304 bf16
  bfu* vtb = kb + 4194304;                 // 4,194,304 bf16
  float* attn = (float*)(vtb + 4194304);   // 4,194,304 f32
  bfu*   lno  = (bfu*)(attn + 4194304);    // 4,194,304 bf16
  float* part = (float*)(lno + 4194304);   // 1,048,576 f32

  k_prep    <<<4288, 256, 0, stream>>>(x, (ushort4*)xb, WQ, WK, WV, wt);
  k_qkv     <<<dim3(64, 12), 256, 0, stream>>>(xb, wt, qb, kb, vtb);
  k_attn    <<<dim3(8, 8, 16), 256, 0, stream>>>(qb, kb, vtb, xb, attn);
  k_ln      <<<8192, 256, 0, stream>>>(attn, lnw, lnb, lno);
  k_lin_mfma<<<1024, 256, 0, stream>>>(lno, Wl, part);
  k_lin_red <<<32, 256, 0, stream>>>(part, bl, out);
}